// Round 1
// baseline (117.776 us; speedup 1.0000x reference)
//
#include <hip/hip_runtime.h>

#define B_   4
#define N_   96
#define DIM_ 128
#define PB   (N_*N_)            // 9216 positions per batch
#define NPOS (B_*PB)            // 36864

// workspace layout (float offsets)
#define OFF_WEFF 0              // [24][128]  effective edge weights (t-major)
#define OFF_CALL 3072           // [24]       combined biases (be@W456, +bt for Z)
#define OFF_TN   3104           // [384][24]  node projections ti/tj/tk (+bn terms)
#define OFF_X    12320          // [4][8][96][96]  X[b][s][i][k] = e_ik + tk
#define OFF_Y    307232         // [4][8][96][96]  Y[b][s][j][k] = e_kj^T
#define OFF_Z    602144         // [4][8][96][96]  Z[b][s][i][j] = e_ij+ti+tj+bt
#define OFF_T    897056         // [4][8][96][96]  T[b][s][i][j] = max_k relu(...)
// total 1,191,968 floats = 4.77 MB

// ---------------------------------------------------------------------------
// K0: combined weights + node projection table.
//   Weff[t][d] = sum_u We[d][u] * Wt[(3+t/8)*8+u][t%8]        (t in [0,24))
//   cAll[t]    = be @ W{4,5,6}  (+ bt for t>=16)
//   TN[p][t]   = node[p] @ (Wn @ W{1,2,3}) + bn @ W{1,2,3}
// blocks 0..31: 12 TN rows each; block 32: Weff + cAll.
// ---------------------------------------------------------------------------
__global__ __launch_bounds__(256) void k0_prep(
    const float* __restrict__ node, const float* __restrict__ Wn,
    const float* __restrict__ bn,   const float* __restrict__ We,
    const float* __restrict__ be,   const float* __restrict__ Wt,
    const float* __restrict__ bt,   float* __restrict__ ws) {
  const int tid = threadIdx.x;
  if (blockIdx.x == 32) {
    for (int idx = tid; idx < 24*128; idx += 256) {
      int t = idx >> 7, d = idx & 127;
      int g = t >> 3, s = t & 7;
      float v = 0.f;
#pragma unroll
      for (int u = 0; u < 8; ++u) v += We[d*8+u] * Wt[((3+g)*8+u)*8 + s];
      ws[OFF_WEFF + t*128 + d] = v;
    }
    if (tid < 24) {
      int g = tid >> 3, s = tid & 7;
      float v = 0.f;
#pragma unroll
      for (int u = 0; u < 8; ++u) v += be[u] * Wt[((3+g)*8+u)*8 + s];
      if (g == 2) v += bt[s];
      ws[OFF_CALL + tid] = v;
    }
  } else {
    __shared__ float ww[24*130];   // [g*8+s][d] padded stride 130
    __shared__ float nl[12*130];   // 12 node rows, padded
    for (int idx = tid; idx < 3*128*8; idx += 256) {
      int g = idx >> 10, rem = idx & 1023;
      int d = rem >> 3, s = rem & 7;
      float v = 0.f;
#pragma unroll
      for (int u = 0; u < 8; ++u) v += Wn[d*8+u] * Wt[(g*8+u)*8 + s];
      ww[(g*8+s)*130 + d] = v;
    }
    const int p0 = blockIdx.x * 12;
    for (int f = tid; f < 12*128; f += 256) {
      int pr = f >> 7, d = f & 127;
      nl[pr*130 + d] = node[(p0+pr)*DIM_ + d];
    }
    __syncthreads();
    for (int idx = tid; idx < 12*24; idx += 256) {
      int pr = idx / 24, t = idx - pr*24;
      int g = t >> 3, s = t & 7;
      float v = 0.f;
#pragma unroll
      for (int u = 0; u < 8; ++u) v += bn[u] * Wt[(g*8+u)*8 + s];
      const float* a = nl + pr*130;
      const float* w = ww + (g*8+s)*130;
#pragma unroll 8
      for (int d = 0; d < 128; ++d) v += a[d] * w[d];
      ws[OFF_TN + (p0+pr)*24 + t] = v;
    }
  }
}

// ---------------------------------------------------------------------------
// K1: project path_emb into X/Y/Z (s-major layouts for K2).
// One block = 48 consecutive positions of one (b,r) row (c0 = 0 or 48).
// Wave w handles t-range [6w, 6w+6): t is wave-uniform -> Weff via s_loads.
// LDS P tile padded to stride 130 (b64 reads at the 4-pass floor).
// ---------------------------------------------------------------------------
__global__ __launch_bounds__(256) void k1_proj(
    const float* __restrict__ P, const float* __restrict__ wsc,
    float* __restrict__ ws) {
  __shared__ float lp[48*130];
  __shared__ float tnl[96*24];
  const int tid = threadIdx.x;
  const int blk = blockIdx.x;
  const int b  = blk / 192;           // 192 blocks per batch
  const int rr = blk - b*192;
  const int r  = rr >> 1;
  const int c0 = (rr & 1) * 48;
  // stage 48 rows x 128 f32, coalesced float4 -> LDS (b64 writes, stride 130)
  const float4* Prow = (const float4*)(P + ((size_t)(b*PB) + r*N_ + c0) * DIM_);
  for (int f = tid; f < 1536; f += 256) {
    float4 v = Prow[f];
    int pos = f >> 5, dd = f & 31;
    float* dst = lp + pos*130 + dd*4;
    ((float2*)dst)[0] = make_float2(v.x, v.y);
    ((float2*)dst)[1] = make_float2(v.z, v.w);
  }
  const float4* tg4 = (const float4*)(wsc + OFF_TN + b*96*24);
  for (int f = tid; f < 576; f += 256) ((float4*)tnl)[f] = tg4[f];
  __syncthreads();

  const int w    = __builtin_amdgcn_readfirstlane((int)(threadIdx.x >> 6));
  const int lane = tid & 63;
  const int t0   = w * 6;
  const int pos  = lane < 48 ? lane : 47;   // lanes 48..63 duplicate, masked at write
  const float* Wg = wsc + OFF_WEFF;
  const float* pa = lp + pos*130;
  float acc[6] = {0.f,0.f,0.f,0.f,0.f,0.f};
#pragma unroll 4
  for (int d = 0; d < 128; d += 2) {
    float2 va = *(const float2*)(pa + d);
#pragma unroll
    for (int tt = 0; tt < 6; ++tt) {
      acc[tt] += va.x * Wg[(t0+tt)*128 + d] + va.y * Wg[(t0+tt)*128 + d + 1];
    }
  }
  if (lane < 48) {
    const int c = c0 + lane;
    float* Xs = ws + OFF_X; float* Ys = ws + OFF_Y; float* Zs = ws + OFF_Z;
#pragma unroll
    for (int tt = 0; tt < 6; ++tt) {
      int t = t0 + tt;
      float val = acc[tt] + wsc[OFF_CALL + t];
      if (t < 8) {                       // X[b][s][i=r][k=c] = e_ik + tk(c)
        val += tnl[c*24 + 16 + t];
        Xs[((b*8+t)*N_ + r)*N_ + c] = val;
      } else if (t < 16) {               // Y[b][s][j=c][k=r] = e_kj
        int s = t - 8;
        Ys[((b*8+s)*N_ + c)*N_ + r] = val;
      } else {                           // Z[b][s][i=r][j=c] = e_ij+ti+tj+bt
        int s = t - 16;
        val += tnl[r*24 + s] + tnl[c*24 + 8 + s];
        Zs[((b*8+s)*N_ + r)*N_ + c] = val;
      }
    }
  }
}

// ---------------------------------------------------------------------------
// K2: T[b,s,i,j] = max_k relu(X[b,s,i,k] + Y[b,s,j,k] + Z[b,s,i,j])
// grid = (b,s) x 4 i-tiles x 4 j-tiles of 24. 4 waves split k (24 each).
// Each lane owns a 3x3 (i,j) register tile: 6 b64 LDS reads per 18 updates.
// ---------------------------------------------------------------------------
__global__ __launch_bounds__(256) void k2_maxplus(
    const float* __restrict__ wsc, float* __restrict__ ws) {
  __shared__ float xs [24*100];
  __shared__ float ysl[24*100];
  __shared__ float zl [24*24];
  __shared__ float red[3*64*9];
  const int tid = threadIdx.x;
  const int bs = blockIdx.x >> 4;                 // b*8+s
  const int it = (blockIdx.x >> 2) & 3;
  const int jt = blockIdx.x & 3;
  const float* Xg = wsc + OFF_X + (bs*N_ + it*24)*N_;
  const float* Yg = wsc + OFF_Y + (bs*N_ + jt*24)*N_;
  const float* Zg = wsc + OFF_Z + (bs*N_ + it*24)*N_ + jt*24;
  for (int f = tid; f < 576; f += 256) {
    int row = f / 24, kk = f - row*24;
    *(float4*)(xs  + row*100 + kk*4) = *(const float4*)(Xg + row*N_ + kk*4);
    *(float4*)(ysl + row*100 + kk*4) = *(const float4*)(Yg + row*N_ + kk*4);
  }
  for (int f = tid; f < 144; f += 256) {
    int row = f / 6, kk = f - row*6;
    *(float4*)(zl + row*24 + kk*4) = *(const float4*)(Zg + row*N_ + kk*4);
  }
  __syncthreads();
  const int kc = tid >> 6, lane = tid & 63;
  const int ig = lane >> 3, jg = lane & 7;
  float z[3][3], m[3][3];
#pragma unroll
  for (int di = 0; di < 3; ++di)
#pragma unroll
    for (int dj = 0; dj < 3; ++dj) {
      z[di][dj] = zl[(ig*3+di)*24 + jg*3 + dj];
      m[di][dj] = 0.f;                 // relu >= 0, so 0-init == max of relus
    }
  const float* xb = xs  + (ig*3)*100 + kc*24;
  const float* yb = ysl + (jg*3)*100 + kc*24;
#pragma unroll 4
  for (int k = 0; k < 24; k += 2) {
    float2 xv[3], yv[3];
#pragma unroll
    for (int d = 0; d < 3; ++d) xv[d] = *(const float2*)(xb + d*100 + k);
#pragma unroll
    for (int d = 0; d < 3; ++d) yv[d] = *(const float2*)(yb + d*100 + k);
#pragma unroll
    for (int di = 0; di < 3; ++di)
#pragma unroll
      for (int dj = 0; dj < 3; ++dj) {
        float v0 = xv[di].x + yv[dj].x + z[di][dj];
        float v1 = xv[di].y + yv[dj].y + z[di][dj];
        m[di][dj] = fmaxf(m[di][dj], fmaxf(v0, 0.f));   // -> v_max3_f32
        m[di][dj] = fmaxf(m[di][dj], fmaxf(v1, 0.f));
      }
  }
  if (kc > 0) {
    float* rp = red + ((kc-1)*64 + lane)*9;
#pragma unroll
    for (int q = 0; q < 9; ++q) rp[q] = m[q/3][q%3];
  }
  __syncthreads();
  if (kc == 0) {
#pragma unroll
    for (int kk = 0; kk < 3; ++kk) {
      const float* rp = red + (kk*64 + lane)*9;
#pragma unroll
      for (int q = 0; q < 9; ++q) m[q/3][q%3] = fmaxf(m[q/3][q%3], rp[q]);
    }
    float* Tg = ws + OFF_T + (bs*N_ + it*24 + ig*3)*N_ + jt*24 + jg*3;
#pragma unroll
    for (int di = 0; di < 3; ++di)
#pragma unroll
      for (int dj = 0; dj < 3; ++dj)
        Tg[di*N_ + dj] = m[di][dj];
  }
}

// ---------------------------------------------------------------------------
// K3: out[b,i,j,:] = relu(T[b,:,i,j] @ Wo + bo). Pure streaming write.
// 512 blocks x 72 positions; thread = (q pos-octet, dq -> 4 d's), float4 store.
// ---------------------------------------------------------------------------
__global__ __launch_bounds__(256) void k3_out(
    const float* __restrict__ wsc, const float* __restrict__ Wo,
    const float* __restrict__ bo,  float* __restrict__ out) {
  __shared__ float ts[8*72];
  const int tid = threadIdx.x;
  const int blk = blockIdx.x;
  const int b   = blk >> 7;                // 128 blocks per batch
  const int off = (blk & 127) * 72;
  const float* Tg = wsc + OFF_T + b*8*PB + off;
  for (int f = tid; f < 144; f += 256) {   // 8 s-slices x 72 = 144 float4
    int s = f / 18, kk = f - s*18;
    *(float4*)(ts + s*72 + kk*4) = *(const float4*)(Tg + s*PB + kk*4);
  }
  __syncthreads();
  const int dq = tid & 31;                 // d = 4*dq .. 4*dq+3
  const int q  = tid >> 5;                 // 9 positions each
  float wo[8][4];
#pragma unroll
  for (int s = 0; s < 8; ++s) {
    float4 wv = *(const float4*)(Wo + s*DIM_ + dq*4);
    wo[s][0]=wv.x; wo[s][1]=wv.y; wo[s][2]=wv.z; wo[s][3]=wv.w;
  }
  float4 bv = *(const float4*)(bo + dq*4);
  const size_t pbase = (size_t)b*PB + off;
  for (int p = 0; p < 9; ++p) {
    int pp = q*9 + p;
    float a0 = bv.x, a1 = bv.y, a2 = bv.z, a3 = bv.w;
#pragma unroll
    for (int s = 0; s < 8; ++s) {
      float tv = ts[s*72 + pp];
      a0 += tv*wo[s][0]; a1 += tv*wo[s][1];
      a2 += tv*wo[s][2]; a3 += tv*wo[s][3];
    }
    float4 o = make_float4(fmaxf(a0,0.f), fmaxf(a1,0.f),
                           fmaxf(a2,0.f), fmaxf(a3,0.f));
    *(float4*)(out + (pbase + pp)*DIM_ + dq*4) = o;
  }
}

extern "C" void kernel_launch(void* const* d_in, const int* in_sizes, int n_in,
                              void* d_out, int out_size, void* d_ws, size_t ws_size,
                              hipStream_t stream) {
  const float* node = (const float*)d_in[0];
  const float* path = (const float*)d_in[1];
  const float* Wn   = (const float*)d_in[2];
  const float* bn   = (const float*)d_in[3];
  const float* We   = (const float*)d_in[4];
  const float* be   = (const float*)d_in[5];
  const float* Wt   = (const float*)d_in[6];
  const float* bt   = (const float*)d_in[7];
  const float* Wo   = (const float*)d_in[8];
  const float* bo   = (const float*)d_in[9];
  float* ws  = (float*)d_ws;
  float* out = (float*)d_out;

  k0_prep   <<<dim3(33),  dim3(256), 0, stream>>>(node, Wn, bn, We, be, Wt, bt, ws);
  k1_proj   <<<dim3(768), dim3(256), 0, stream>>>(path, ws, ws);
  k2_maxplus<<<dim3(512), dim3(256), 0, stream>>>(ws, ws);
  k3_out    <<<dim3(512), dim3(256), 0, stream>>>(ws, Wo, bo, out);
}